// Round 5
// baseline (1831.672 us; speedup 1.0000x reference)
//
#include <hip/hip_runtime.h>
#include <cstddef>

// ---- problem constants ----
#define NN     50000
#define NE     800000
#define IND    128
#define EMBD   64
#define IN1    192     // IND + EMBD
#define HDIM   256
#define RR     12
#define BB     8
#define NGENE  20000
#define NPATH  2000
#define NRK    (RR * NN)               // 600000 segment keys
#define SCB    1024
#define NSB    ((NRK + SCB - 1) / SCB) // 586

typedef __attribute__((ext_vector_type(8))) short short8;
typedef __attribute__((ext_vector_type(4))) float f32x4;
typedef unsigned short ushortT;

__device__ __forceinline__ float bu2f(unsigned short u) {
  unsigned int x = ((unsigned int)u) << 16;
  return __builtin_bit_cast(float, x);
}
__device__ __forceinline__ unsigned short f2bu(float f) {
  unsigned int x = __builtin_bit_cast(unsigned int, f);
  unsigned int r = (x + 0x7fffu + ((x >> 16) & 1u)) >> 16;
  return (unsigned short)r;
}

// ---------- build x0 = [x | 0] bf16 ----------
__global__ void k_build_x0(const float* __restrict__ x, ushortT* __restrict__ x0) {
  int t = blockIdx.x * 256 + threadIdx.x;
  if (t >= NN * IN1) return;
  int n = t / IN1, i = t - n * IN1;
  x0[t] = (i < IND) ? f2bu(x[(size_t)n * IND + i]) : (ushortT)0;
}

__global__ void k_add_emb(const int* __restrict__ idx, const float* __restrict__ emb,
                          ushortT* __restrict__ x0, int count) {
  int t = blockIdx.x * 256 + threadIdx.x;
  if (t >= count * EMBD) return;
  int g = t / EMBD, j = t - g * EMBD;
  x0[(size_t)idx[g] * IN1 + IND + j] = f2bu(emb[t]);
}

// ---------- per-(rel,dst) edge counts ----------
__global__ void k_count(const int* __restrict__ ei, const int* __restrict__ et,
                        int* __restrict__ cnt) {
  int e = blockIdx.x * 256 + threadIdx.x;
  if (e >= NE) return;
  atomicAdd(&cnt[et[e] * NN + ei[NE + e]], 1);
}

// ---------- 3-kernel exclusive scan ----------
__global__ __launch_bounds__(256) void k_scan1(const int* __restrict__ cnt,
                                               int* __restrict__ bsum) {
  __shared__ int lds[256];
  int t = threadIdx.x;
  int base = blockIdx.x * SCB + t * 4;
  int s = 0;
#pragma unroll
  for (int j = 0; j < 4; j++) { int idx = base + j; if (idx < NRK) s += cnt[idx]; }
  lds[t] = s; __syncthreads();
  for (int d = 128; d > 0; d >>= 1) { if (t < d) lds[t] += lds[t + d]; __syncthreads(); }
  if (t == 0) bsum[blockIdx.x] = lds[0];
}

__global__ __launch_bounds__(1024) void k_scan2(const int* __restrict__ bsum,
                                                int* __restrict__ bscan) {
  __shared__ int lds[1024];
  int t = threadIdx.x;
  int v = (t < NSB) ? bsum[t] : 0;
  lds[t] = v; __syncthreads();
  for (int d = 1; d < 1024; d <<= 1) {
    int add = (t >= d) ? lds[t - d] : 0; __syncthreads();
    lds[t] += add; __syncthreads();
  }
  if (t < NSB) bscan[t] = lds[t] - v;
}

__global__ __launch_bounds__(256) void k_scan3(const int* __restrict__ cnt,
                                               const int* __restrict__ bscan,
                                               int* __restrict__ off) {
  __shared__ int lds[256];
  int t = threadIdx.x;
  int base = blockIdx.x * SCB + t * 4;
  int v[4]; int s = 0;
#pragma unroll
  for (int j = 0; j < 4; j++) { int idx = base + j; v[j] = (idx < NRK) ? cnt[idx] : 0; s += v[j]; }
  lds[t] = s; __syncthreads();
  for (int d = 1; d < 256; d <<= 1) {
    int add = (t >= d) ? lds[t - d] : 0; __syncthreads();
    lds[t] += add; __syncthreads();
  }
  int ex = lds[t] - s + bscan[blockIdx.x];
#pragma unroll
  for (int j = 0; j < 4; j++) {
    int idx = base + j;
    if (idx < NRK) { off[idx] = ex; ex += v[j]; }
  }
}

__global__ void k_fill(const int* __restrict__ ei, const int* __restrict__ et,
                       const int* __restrict__ off, int* __restrict__ fill,
                       int* __restrict__ perm) {
  int e = blockIdx.x * 256 + threadIdx.x;
  if (e >= NE) return;
  int key = et[e] * NN + ei[NE + e];
  int pos = off[key] + atomicAdd(&fill[key], 1);
  perm[pos] = e;
}

// ---------- W[r][o][i] = bf16( sum_b comp[r,b]*basis[b,i,o] ); W = Wall + 256*in ----------
__global__ void k_wcat(const float* __restrict__ comp, const float* __restrict__ basis,
                       ushortT* __restrict__ W, int in_dim) {
  int t = blockIdx.x * 256 + threadIdx.x;
  int total = RR * HDIM * in_dim;
  if (t >= total) return;
  int i = t % in_dim;
  int o = (t / in_dim) & 255;
  int r = t / (in_dim * 256);
  float acc = 0.f;
#pragma unroll
  for (int b = 0; b < BB; b++)
    acc += comp[r * BB + b] * basis[((size_t)b * in_dim + i) * HDIM + o];
  W[t] = f2bu(acc);
}

// ---------- root transpose into Wall seg 0: rt[o][i] = bf16(root[i][o]) ----------
__global__ void k_troot(const float* __restrict__ root, ushortT* __restrict__ rt,
                        int in_dim) {
  int t = blockIdx.x * 256 + threadIdx.x;
  if (t >= in_dim * HDIM) return;
  int i = t % in_dim, o = t / in_dim;
  rt[t] = f2bu(root[(size_t)i * HDIM + o]);
}

// ---------- fused conv: gather-aggregate + 13-segment MFMA GEMM + bias + head-softmax ----------
// block: 512 threads = 8 waves; M-tile 128 dsts, N = 256 (full width)
// wave (wr,wc): wr=wv>>2 rows wr*64.., wc=wv&3 cols wc*64.. ; per wave 4x4 mfma 16x16x32
// LDS A-tile 128x64 bf16, xor-swizzled: chunk' = chunk ^ (row&7). B-frags direct from L2.
__global__ __launch_bounds__(512) void k_conv(const ushortT* __restrict__ xin,
                                              const int* __restrict__ ei,
                                              const int* __restrict__ perm,
                                              const int* __restrict__ off,
                                              const int* __restrict__ cnt,
                                              const ushortT* __restrict__ Wall,
                                              const float* __restrict__ bias,
                                              const float* __restrict__ att,
                                              ushortT* __restrict__ hout,
                                              int in_dim) {
  __shared__ ushortT As[128 * 64];
  __shared__ float sm[128][4];
  const int tid = threadIdx.x;
  const int bm = blockIdx.x * 128;
  const int wv = tid >> 6, l = tid & 63;
  const int wr = wv >> 2, wc = wv & 3;
  const int lm = l & 15, lq = l >> 4;
  const int c8 = tid & 7;        // staging: 16B chunk id
  const int d0 = tid >> 3;       // staging: dst-local base (0..63)
  const int nkt = in_dim >> 6;

  f32x4 acc[4][4];
#pragma unroll
  for (int mt = 0; mt < 4; mt++)
#pragma unroll
    for (int nt = 0; nt < 4; nt++) acc[mt][nt] = (f32x4){0.f, 0.f, 0.f, 0.f};

  for (int seg = 0; seg < 13; seg++) {
    const ushortT* Wseg = Wall + (size_t)seg * 256 * in_dim;
    for (int kt = 0; kt < nkt; kt++) {
      __syncthreads();
      // ---- stage A-tile (128 x 64 bf16) ----
#pragma unroll
      for (int half = 0; half < 2; half++) {
        int dl = d0 + half * 64;
        int dst = bm + dl;
        uint4 pack = make_uint4(0u, 0u, 0u, 0u);
        if (seg == 0) {
          if (dst < NN)
            pack = *(const uint4*)(xin + (size_t)dst * in_dim + kt * 64 + c8 * 8);
        } else if (dst < NN) {
          int key = (seg - 1) * NN + dst;
          int beg = off[key];
          int n = cnt[key];
          float a0=0.f,a1=0.f,a2=0.f,a3=0.f,a4=0.f,a5=0.f,a6=0.f,a7=0.f;
          for (int p = 0; p < n; p++) {
            int src = ei[perm[beg + p]];
            uint4 v = *(const uint4*)(xin + (size_t)src * in_dim + kt * 64 + c8 * 8);
            a0 += bu2f((ushortT)(v.x & 0xffff)); a1 += bu2f((ushortT)(v.x >> 16));
            a2 += bu2f((ushortT)(v.y & 0xffff)); a3 += bu2f((ushortT)(v.y >> 16));
            a4 += bu2f((ushortT)(v.z & 0xffff)); a5 += bu2f((ushortT)(v.z >> 16));
            a6 += bu2f((ushortT)(v.w & 0xffff)); a7 += bu2f((ushortT)(v.w >> 16));
          }
          float s = 1.0f / (float)max(n, 1);
          pack.x = (unsigned)f2bu(a0 * s) | ((unsigned)f2bu(a1 * s) << 16);
          pack.y = (unsigned)f2bu(a2 * s) | ((unsigned)f2bu(a3 * s) << 16);
          pack.z = (unsigned)f2bu(a4 * s) | ((unsigned)f2bu(a5 * s) << 16);
          pack.w = (unsigned)f2bu(a6 * s) | ((unsigned)f2bu(a7 * s) << 16);
        }
        *(uint4*)(&As[dl * 64 + (c8 ^ (dl & 7)) * 8]) = pack;
      }
      __syncthreads();
      // ---- MFMA: 2 k-steps of 32 ----
#pragma unroll
      for (int ks = 0; ks < 2; ks++) {
        short8 af[4], bf[4];
#pragma unroll
        for (int mt = 0; mt < 4; mt++) {
          int ar = wr * 64 + mt * 16 + lm;
          af[mt] = *(const short8*)(&As[ar * 64 + (((ks * 4) + lq) ^ (ar & 7)) * 8]);
        }
#pragma unroll
        for (int nt = 0; nt < 4; nt++) {
          int orow = wc * 64 + nt * 16 + lm;
          bf[nt] = *(const short8*)(Wseg + (size_t)orow * in_dim + kt * 64 + ks * 32 + lq * 8);
        }
#pragma unroll
        for (int mt = 0; mt < 4; mt++)
#pragma unroll
          for (int nt = 0; nt < 4; nt++)
            acc[mt][nt] = __builtin_amdgcn_mfma_f32_16x16x32_bf16(af[mt], bf[nt],
                                                                  acc[mt][nt], 0, 0, 0);
      }
    }
  }

  // ---- epilogue: bias + head-softmax attention + bf16 store ----
  float bv[4], av[4];
#pragma unroll
  for (int nt = 0; nt < 4; nt++) {
    bv[nt] = bias[wc * 64 + nt * 16 + lm];
    av[nt] = att[wc * 64 + nt * 16 + lm];
  }
#pragma unroll
  for (int mt = 0; mt < 4; mt++)
#pragma unroll
    for (int nt = 0; nt < 4; nt++)
#pragma unroll
      for (int r = 0; r < 4; r++) acc[mt][nt][r] += bv[nt];

  // per-row partial head score: head index == wc (cols wc*64..wc*64+63)
#pragma unroll
  for (int mt = 0; mt < 4; mt++) {
    float sr[4];
#pragma unroll
    for (int r = 0; r < 4; r++)
      sr[r] = acc[mt][0][r] * av[0] + acc[mt][1][r] * av[1] +
              acc[mt][2][r] * av[2] + acc[mt][3][r] * av[3];
#pragma unroll
    for (int o = 1; o <= 8; o <<= 1) {
#pragma unroll
      for (int r = 0; r < 4; r++) sr[r] += __shfl_xor(sr[r], o, 64);
    }
    if (lm == 0) {
#pragma unroll
      for (int r = 0; r < 4; r++) sm[wr * 64 + mt * 16 + lq * 4 + r][wc] = sr[r];
    }
  }
  __syncthreads();
  if (tid < 128) {
    float s0 = sm[tid][0], s1 = sm[tid][1], s2 = sm[tid][2], s3 = sm[tid][3];
    float mx = fmaxf(fmaxf(s0, s1), fmaxf(s2, s3));
    float e0 = __expf(s0 - mx), e1 = __expf(s1 - mx), e2 = __expf(s2 - mx), e3 = __expf(s3 - mx);
    float inv = 1.0f / (e0 + e1 + e2 + e3);
    sm[tid][0] = e0 * inv; sm[tid][1] = e1 * inv; sm[tid][2] = e2 * inv; sm[tid][3] = e3 * inv;
  }
  __syncthreads();
#pragma unroll
  for (int mt = 0; mt < 4; mt++) {
#pragma unroll
    for (int r = 0; r < 4; r++) {
      int rl = wr * 64 + mt * 16 + lq * 4 + r;
      int row = bm + rl;
      if (row >= NN) continue;
      float al = sm[rl][wc];
      ushortT* op = hout + (size_t)row * HDIM + wc * 64;
#pragma unroll
      for (int nt = 0; nt < 4; nt++)
        op[nt * 16 + lm] = f2bu(acc[mt][nt][r] * al);
    }
  }
}

// ---------- prediction head: bf16 h, fp32 weights ----------
__global__ void k_pred(const ushortT* __restrict__ h, const float* __restrict__ w,
                       const float* __restrict__ b, float* __restrict__ out) {
  int t = blockIdx.x * 256 + threadIdx.x;
  if (t >= NN * 12) return;
  int n = t / 12, j = t - n * 12;
  float acc = b[j];
  const ushortT* hp = h + (size_t)n * HDIM;
#pragma unroll 4
  for (int k = 0; k < HDIM; k++) acc += bu2f(hp[k]) * w[k * 12 + j];
  out[t] = acc;
}

extern "C" void kernel_launch(void* const* d_in, const int* in_sizes, int n_in,
                              void* d_out, int out_size, void* d_ws, size_t ws_size,
                              hipStream_t stream) {
  const float* x         = (const float*)d_in[0];
  const int*   edge_idx  = (const int*)d_in[1];
  const int*   edge_type = (const int*)d_in[2];
  const int*   gene_idx  = (const int*)d_in[3];
  const int*   path_idx  = (const int*)d_in[4];
  const float* gene_emb  = (const float*)d_in[5];
  const float* path_emb  = (const float*)d_in[6];
  const float* comp1     = (const float*)d_in[7];
  const float* basis1    = (const float*)d_in[8];
  const float* root1     = (const float*)d_in[9];
  const float* bias1     = (const float*)d_in[10];
  const float* att1      = (const float*)d_in[11];
  const float* comp2     = (const float*)d_in[12];
  const float* basis2    = (const float*)d_in[13];
  const float* root2     = (const float*)d_in[14];
  const float* bias2     = (const float*)d_in[15];
  const float* att2      = (const float*)d_in[16];
  const float* pred_w    = (const float*)d_in[17];
  const float* pred_b    = (const float*)d_in[18];
  float* out = (float*)d_out;

  // workspace layout (bytes, 16B aligned); total ~84 MB
  char* ws = (char*)d_ws;
  ushortT* x0b   = (ushortT*)(ws);               // 19,200,000
  ushortT* h1b   = (ushortT*)(ws + 19200000);    // 25,600,000
  ushortT* h2b   = (ushortT*)(ws + 44800000);    // 25,600,000
  ushortT* Wall1 = (ushortT*)(ws + 70400000);    // 13*256*192*2 = 1,277,952
  ushortT* Wall2 = (ushortT*)(ws + 71677952);    // 13*256*256*2 = 1,703,936
  int*     cnt   = (int*)(ws + 73381888);        // 2,400,000
  int*     off   = (int*)(ws + 75781888);        // 2,400,000
  int*     fill  = (int*)(ws + 78181888);        // 2,400,000
  int*     perm  = (int*)(ws + 80581888);        // 3,200,000
  int*     bsum  = (int*)(ws + 83781888);        // 4 KB
  int*     bscan = (int*)(ws + 83785984);        // 4 KB

  dim3 blk(256);

  // ---- stage 0: features + CSR build + weight prep ----
  k_build_x0<<<dim3((NN * IN1) / 256), blk, 0, stream>>>(x, x0b);
  k_add_emb<<<dim3((NGENE * EMBD) / 256), blk, 0, stream>>>(gene_idx, gene_emb, x0b, NGENE);
  k_add_emb<<<dim3((NPATH * EMBD) / 256), blk, 0, stream>>>(path_idx, path_emb, x0b, NPATH);
  hipMemsetAsync(cnt, 0, NRK * 4, stream);
  hipMemsetAsync(fill, 0, NRK * 4, stream);
  k_count<<<dim3(NE / 256), blk, 0, stream>>>(edge_idx, edge_type, cnt);
  k_scan1<<<dim3(NSB), blk, 0, stream>>>(cnt, bsum);
  k_scan2<<<dim3(1), dim3(1024), 0, stream>>>(bsum, bscan);
  k_scan3<<<dim3(NSB), blk, 0, stream>>>(cnt, bscan, off);
  k_fill<<<dim3(NE / 256), blk, 0, stream>>>(edge_idx, edge_type, off, fill, perm);
  k_troot<<<dim3((IN1 * HDIM) / 256), blk, 0, stream>>>(root1, Wall1, IN1);
  k_troot<<<dim3((HDIM * HDIM) / 256), blk, 0, stream>>>(root2, Wall2, HDIM);
  k_wcat<<<dim3((RR * HDIM * IN1) / 256), blk, 0, stream>>>(comp1, basis1, Wall1 + 256 * IN1, IN1);
  k_wcat<<<dim3((RR * HDIM * HDIM) / 256), blk, 0, stream>>>(comp2, basis2, Wall2 + 256 * HDIM, HDIM);

  // ---- fused convs: one dispatch each ----
  dim3 cgrid(391);   // 391*128 = 50048 rows
  dim3 cblk(512);
  k_conv<<<cgrid, cblk, 0, stream>>>(x0b, edge_idx, perm, off, cnt, Wall1, bias1, att1, h1b, IN1);
  k_conv<<<cgrid, cblk, 0, stream>>>(h1b, edge_idx, perm, off, cnt, Wall2, bias2, att2, h2b, HDIM);

  // ---- prediction head ----
  k_pred<<<dim3((NN * 12 + 255) / 256), blk, 0, stream>>>(h2b, pred_w, pred_b, out);
}

// Round 6
// 1256.368 us; speedup vs baseline: 1.4579x; 1.4579x over previous
//
#include <hip/hip_runtime.h>
#include <cstddef>

// ---- problem constants ----
#define NN     50000
#define NE     800000
#define IND    128
#define EMBD   64
#define IN1    192     // IND + EMBD
#define HDIM   256
#define RR     12
#define BB     8
#define NGENE  20000
#define NPATH  2000
#define NRK    (RR * NN)               // 600000 segment keys
#define SCB    1024
#define NSB    ((NRK + SCB - 1) / SCB) // 586

typedef __attribute__((ext_vector_type(8))) short short8;
typedef __attribute__((ext_vector_type(4))) float f32x4;
typedef unsigned short ushortT;

__device__ __forceinline__ float bu2f(unsigned short u) {
  unsigned int x = ((unsigned int)u) << 16;
  return __builtin_bit_cast(float, x);
}
__device__ __forceinline__ unsigned short f2bu(float f) {
  unsigned int x = __builtin_bit_cast(unsigned int, f);
  unsigned int r = (x + 0x7fffu + ((x >> 16) & 1u)) >> 16;
  return (unsigned short)r;
}

// ---------- build x0 = [x | 0] bf16 ----------
__global__ void k_build_x0(const float* __restrict__ x, ushortT* __restrict__ x0) {
  int t = blockIdx.x * 256 + threadIdx.x;
  if (t >= NN * IN1) return;
  int n = t / IN1, i = t - n * IN1;
  x0[t] = (i < IND) ? f2bu(x[(size_t)n * IND + i]) : (ushortT)0;
}

__global__ void k_add_emb(const int* __restrict__ idx, const float* __restrict__ emb,
                          ushortT* __restrict__ x0, int count) {
  int t = blockIdx.x * 256 + threadIdx.x;
  if (t >= count * EMBD) return;
  int g = t / EMBD, j = t - g * EMBD;
  x0[(size_t)idx[g] * IN1 + IND + j] = f2bu(emb[t]);
}

// ---------- per-(rel,dst) edge counts ----------
__global__ void k_count(const int* __restrict__ ei, const int* __restrict__ et,
                        int* __restrict__ cnt) {
  int e = blockIdx.x * 256 + threadIdx.x;
  if (e >= NE) return;
  atomicAdd(&cnt[et[e] * NN + ei[NE + e]], 1);
}

// ---------- 3-kernel exclusive scan ----------
__global__ __launch_bounds__(256) void k_scan1(const int* __restrict__ cnt,
                                               int* __restrict__ bsum) {
  __shared__ int lds[256];
  int t = threadIdx.x;
  int base = blockIdx.x * SCB + t * 4;
  int s = 0;
#pragma unroll
  for (int j = 0; j < 4; j++) { int idx = base + j; if (idx < NRK) s += cnt[idx]; }
  lds[t] = s; __syncthreads();
  for (int d = 128; d > 0; d >>= 1) { if (t < d) lds[t] += lds[t + d]; __syncthreads(); }
  if (t == 0) bsum[blockIdx.x] = lds[0];
}

__global__ __launch_bounds__(1024) void k_scan2(const int* __restrict__ bsum,
                                                int* __restrict__ bscan) {
  __shared__ int lds[1024];
  int t = threadIdx.x;
  int v = (t < NSB) ? bsum[t] : 0;
  lds[t] = v; __syncthreads();
  for (int d = 1; d < 1024; d <<= 1) {
    int add = (t >= d) ? lds[t - d] : 0; __syncthreads();
    lds[t] += add; __syncthreads();
  }
  if (t < NSB) bscan[t] = lds[t] - v;
}

__global__ __launch_bounds__(256) void k_scan3(const int* __restrict__ cnt,
                                               const int* __restrict__ bscan,
                                               int* __restrict__ off) {
  __shared__ int lds[256];
  int t = threadIdx.x;
  int base = blockIdx.x * SCB + t * 4;
  int v[4]; int s = 0;
#pragma unroll
  for (int j = 0; j < 4; j++) { int idx = base + j; v[j] = (idx < NRK) ? cnt[idx] : 0; s += v[j]; }
  lds[t] = s; __syncthreads();
  for (int d = 1; d < 256; d <<= 1) {
    int add = (t >= d) ? lds[t - d] : 0; __syncthreads();
    lds[t] += add; __syncthreads();
  }
  int ex = lds[t] - s + bscan[blockIdx.x];
#pragma unroll
  for (int j = 0; j < 4; j++) {
    int idx = base + j;
    if (idx < NRK) { off[idx] = ex; ex += v[j]; }
  }
}

// stores SRC node id directly (kills one indirection in k_agg)
__global__ void k_fill(const int* __restrict__ ei, const int* __restrict__ et,
                       const int* __restrict__ off, int* __restrict__ fill,
                       int* __restrict__ srcs) {
  int e = blockIdx.x * 256 + threadIdx.x;
  if (e >= NE) return;
  int key = et[e] * NN + ei[NE + e];
  int pos = off[key] + atomicAdd(&fill[key], 1);
  srcs[pos] = ei[e];
}

// ---------- W[r][o][i] = bf16( sum_b comp[r,b]*basis[b,i,o] ) ----------
__global__ void k_wcat(const float* __restrict__ comp, const float* __restrict__ basis,
                       ushortT* __restrict__ W, int in_dim) {
  int t = blockIdx.x * 256 + threadIdx.x;
  int total = RR * HDIM * in_dim;
  if (t >= total) return;
  int i = t % in_dim;
  int o = (t / in_dim) & 255;
  int r = t / (in_dim * 256);
  float acc = 0.f;
#pragma unroll
  for (int b = 0; b < BB; b++)
    acc += comp[r * BB + b] * basis[((size_t)b * in_dim + i) * HDIM + o];
  W[t] = f2bu(acc);
}

__global__ void k_troot(const float* __restrict__ root, ushortT* __restrict__ rt,
                        int in_dim) {
  int t = blockIdx.x * 256 + threadIdx.x;
  if (t >= in_dim * HDIM) return;
  int i = t % in_dim, o = t / in_dim;
  rt[t] = f2bu(root[(size_t)i * HDIM + o]);
}

// ---------- CSR gather aggregation: one wave per (dst, rl); 4 rels per pass ----------
__global__ __launch_bounds__(256) void k_agg(const int* __restrict__ srcs,
                                             const int* __restrict__ off,
                                             const int* __restrict__ cnt,
                                             const ushortT* __restrict__ xin,
                                             ushortT* __restrict__ aggB,
                                             int in_dim, int r0) {
  int wave = (blockIdx.x * 256 + threadIdx.x) >> 6;
  int lane = threadIdx.x & 63;
  int dst = wave >> 2;
  int rl  = wave & 3;
  if (dst >= NN) return;
  int key = (r0 + rl) * NN + dst;
  int beg = off[key];
  int n   = cnt[key];
  bool act = lane * 4 < in_dim;
  float a0 = 0.f, a1 = 0.f, a2 = 0.f, a3 = 0.f;
  for (int p = 0; p < n; p++) {
    int src = srcs[beg + p];
    if (act) {
      ushort4 v = *(const ushort4*)(xin + (size_t)src * in_dim + lane * 4);
      a0 += bu2f(v.x); a1 += bu2f(v.y); a2 += bu2f(v.z); a3 += bu2f(v.w);
    }
  }
  if (act) {
    float s = 1.0f / (float)max(n, 1);
    ushort4 o;
    o.x = f2bu(a0 * s); o.y = f2bu(a1 * s); o.z = f2bu(a2 * s); o.w = f2bu(a3 * s);
    *(ushort4*)(aggB + ((size_t)dst * 4 + rl) * in_dim + lane * 4) = o;
  }
}

// ---------- multi-segment MFMA GEMM with register-resident C across segments ----------
// block 512 thr = 8 waves (wr 0..1 x wc 0..3); M-tile 128, N=256 (full width)
// A streamed from global (xin for seg0 of mode0, aggB rels otherwise) via
// software-pipelined regs -> xor-swizzled LDS (proven 0 conflicts).
// B frags read direct from L2-resident weights.
// mode 0: C = acc + bias (through-LDS coalesced store)
// mode 1: C += acc       (through-LDS RMW)
// mode 2: acc += C; head-softmax attention; bf16 h store
__global__ __launch_bounds__(512) void k_gemm(const ushortT* __restrict__ xin,
                                              const ushortT* __restrict__ aggB,
                                              const ushortT* __restrict__ Wchunk,
                                              float* __restrict__ C,
                                              const float* __restrict__ bias,
                                              const float* __restrict__ att,
                                              ushortT* __restrict__ hout,
                                              int in_dim, int nseg, int mode) {
  __shared__ ushortT As[128 * 64];
  __shared__ float sm[128][4];
  const int tid = threadIdx.x;
  const int bm = blockIdx.x * 128;
  const int wv = tid >> 6, l = tid & 63;
  const int wr = wv >> 2, wc = wv & 3;
  const int lm = l & 15, lq = l >> 4;
  const int c8 = tid & 7;       // 16B chunk within 64-elem row
  const int d0 = tid >> 3;      // 0..63
  const int nkt = in_dim >> 6;
  const int first = (mode == 0) ? 1 : 0;
  const int totKt = nseg * nkt;

  f32x4 acc[4][4];
#pragma unroll
  for (int mt = 0; mt < 4; mt++)
#pragma unroll
    for (int nt = 0; nt < 4; nt++) acc[mt][nt] = (f32x4){0.f, 0.f, 0.f, 0.f};

  // prefetch (seg=0, kt=0)
  uint4 pv0, pv1;
  {
    const ushortT* ab; size_t str;
    if (first) { ab = xin; str = (size_t)in_dim; }
    else       { ab = aggB; str = (size_t)4 * in_dim; }
    int dA = bm + d0, dB = dA + 64;
    pv0 = (dA < NN) ? *(const uint4*)(ab + (size_t)dA * str + c8 * 8) : make_uint4(0u,0u,0u,0u);
    pv1 = (dB < NN) ? *(const uint4*)(ab + (size_t)dB * str + c8 * 8) : make_uint4(0u,0u,0u,0u);
  }
  int segC = 0, ktC = 0;
  for (int t = 0; t < totKt; t++) {
    __syncthreads();
    *(uint4*)(&As[d0 * 64 + (c8 ^ (d0 & 7)) * 8]) = pv0;
    int dl = d0 + 64;
    *(uint4*)(&As[dl * 64 + (c8 ^ (dl & 7)) * 8]) = pv1;
    __syncthreads();
    // prefetch next tile
    int segP = segC, ktP = ktC + 1;
    if (ktP == nkt) { ktP = 0; segP++; }
    if (t + 1 < totKt) {
      const ushortT* ab; size_t str;
      if (first && segP == 0) { ab = xin; str = (size_t)in_dim; }
      else { int rl = segP - first; ab = aggB + (size_t)rl * in_dim; str = (size_t)4 * in_dim; }
      int koff = ktP * 64 + c8 * 8;
      int dA = bm + d0, dB = dA + 64;
      pv0 = (dA < NN) ? *(const uint4*)(ab + (size_t)dA * str + koff) : make_uint4(0u,0u,0u,0u);
      pv1 = (dB < NN) ? *(const uint4*)(ab + (size_t)dB * str + koff) : make_uint4(0u,0u,0u,0u);
    }
    // MFMA on current tile
    const ushortT* Wseg = Wchunk + (size_t)segC * 256 * in_dim + ktC * 64;
#pragma unroll
    for (int ks = 0; ks < 2; ks++) {
      short8 af[4], bf[4];
#pragma unroll
      for (int mt = 0; mt < 4; mt++) {
        int ar = wr * 64 + mt * 16 + lm;
        af[mt] = *(const short8*)(&As[ar * 64 + (((ks * 4) + lq) ^ (ar & 7)) * 8]);
      }
#pragma unroll
      for (int nt = 0; nt < 4; nt++) {
        int orow = wc * 64 + nt * 16 + lm;
        bf[nt] = *(const short8*)(Wseg + (size_t)orow * in_dim + ks * 32 + lq * 8);
      }
#pragma unroll
      for (int mt = 0; mt < 4; mt++)
#pragma unroll
        for (int nt = 0; nt < 4; nt++)
          acc[mt][nt] = __builtin_amdgcn_mfma_f32_16x16x32_bf16(af[mt], bf[nt],
                                                                acc[mt][nt], 0, 0, 0);
    }
    segC = segP; ktC = ktP;
  }

  if (mode == 2) {
    // fold in prior chunks' C, then fused head-softmax attention
#pragma unroll
    for (int mt = 0; mt < 4; mt++)
#pragma unroll
      for (int r = 0; r < 4; r++) {
        int row = bm + wr * 64 + mt * 16 + lq * 4 + r;
        if (row < NN) {
          const float* cp = C + (size_t)row * HDIM + wc * 64;
#pragma unroll
          for (int nt = 0; nt < 4; nt++) acc[mt][nt][r] += cp[nt * 16 + lm];
        }
      }
    float av[4];
#pragma unroll
    for (int nt = 0; nt < 4; nt++) av[nt] = att[wc * 64 + nt * 16 + lm];
#pragma unroll
    for (int mt = 0; mt < 4; mt++) {
      float sr[4];
#pragma unroll
      for (int r = 0; r < 4; r++)
        sr[r] = acc[mt][0][r] * av[0] + acc[mt][1][r] * av[1] +
                acc[mt][2][r] * av[2] + acc[mt][3][r] * av[3];
#pragma unroll
      for (int o = 1; o <= 8; o <<= 1) {
#pragma unroll
        for (int r = 0; r < 4; r++) sr[r] += __shfl_xor(sr[r], o, 64);
      }
      if (lm == 0) {
#pragma unroll
        for (int r = 0; r < 4; r++) sm[wr * 64 + mt * 16 + lq * 4 + r][wc] = sr[r];
      }
    }
    __syncthreads();
    if (tid < 128) {
      float s0 = sm[tid][0], s1 = sm[tid][1], s2 = sm[tid][2], s3 = sm[tid][3];
      float mx = fmaxf(fmaxf(s0, s1), fmaxf(s2, s3));
      float e0 = __expf(s0 - mx), e1 = __expf(s1 - mx), e2 = __expf(s2 - mx), e3 = __expf(s3 - mx);
      float inv = 1.0f / (e0 + e1 + e2 + e3);
      sm[tid][0] = e0 * inv; sm[tid][1] = e1 * inv; sm[tid][2] = e2 * inv; sm[tid][3] = e3 * inv;
    }
    __syncthreads();
#pragma unroll
    for (int mt = 0; mt < 4; mt++) {
#pragma unroll
      for (int r = 0; r < 4; r++) {
        int rl = wr * 64 + mt * 16 + lq * 4 + r;
        int row = bm + rl;
        if (row >= NN) continue;
        float al = sm[rl][wc];
        ushortT* op = hout + (size_t)row * HDIM + wc * 64;
#pragma unroll
        for (int nt = 0; nt < 4; nt++)
          op[nt * 16 + lm] = f2bu(acc[mt][nt][r] * al);
      }
    }
  } else {
    // through-LDS coalesced fp32 C write (16-row slices, full-line stores)
    float* Asf = (float*)As;
    for (int s8 = 0; s8 < 8; s8++) {
      __syncthreads();
      if (wr == (s8 >> 2)) {
        int mt = s8 & 3;
#pragma unroll
        for (int r = 0; r < 4; r++)
#pragma unroll
          for (int nt = 0; nt < 4; nt++)
            Asf[(lq * 4 + r) * 256 + wc * 64 + nt * 16 + lm] = acc[mt][nt][r];
      }
      __syncthreads();
      int base = tid * 8;
      int lr = base >> 8, lc = base & 255;
      int grow = bm + s8 * 16 + lr;
      if (grow < NN) {
        float v[8];
#pragma unroll
        for (int j = 0; j < 8; j++) v[j] = Asf[lr * 256 + lc + j];
        float* cp = C + (size_t)grow * HDIM + lc;
        if (mode == 1) {
#pragma unroll
          for (int j = 0; j < 8; j++) v[j] += cp[j];
        } else {
#pragma unroll
          for (int j = 0; j < 8; j++) v[j] += bias[lc + j];
        }
        float4 w0 = {v[0], v[1], v[2], v[3]};
        float4 w1 = {v[4], v[5], v[6], v[7]};
        *(float4*)cp = w0;
        *(float4*)(cp + 4) = w1;
      }
    }
  }
}

// ---------- prediction head: bf16 h, fp32 weights ----------
__global__ void k_pred(const ushortT* __restrict__ h, const float* __restrict__ w,
                       const float* __restrict__ b, float* __restrict__ out) {
  int t = blockIdx.x * 256 + threadIdx.x;
  if (t >= NN * 12) return;
  int n = t / 12, j = t - n * 12;
  float acc = b[j];
  const ushortT* hp = h + (size_t)n * HDIM;
#pragma unroll 4
  for (int k = 0; k < HDIM; k++) acc += bu2f(hp[k]) * w[k * 12 + j];
  out[t] = acc;
}

extern "C" void kernel_launch(void* const* d_in, const int* in_sizes, int n_in,
                              void* d_out, int out_size, void* d_ws, size_t ws_size,
                              hipStream_t stream) {
  const float* x         = (const float*)d_in[0];
  const int*   edge_idx  = (const int*)d_in[1];
  const int*   edge_type = (const int*)d_in[2];
  const int*   gene_idx  = (const int*)d_in[3];
  const int*   path_idx  = (const int*)d_in[4];
  const float* gene_emb  = (const float*)d_in[5];
  const float* path_emb  = (const float*)d_in[6];
  const float* comp1     = (const float*)d_in[7];
  const float* basis1    = (const float*)d_in[8];
  const float* root1     = (const float*)d_in[9];
  const float* bias1     = (const float*)d_in[10];
  const float* att1      = (const float*)d_in[11];
  const float* comp2     = (const float*)d_in[12];
  const float* basis2    = (const float*)d_in[13];
  const float* root2     = (const float*)d_in[14];
  const float* bias2     = (const float*)d_in[15];
  const float* att2      = (const float*)d_in[16];
  const float* pred_w    = (const float*)d_in[17];
  const float* pred_b    = (const float*)d_in[18];
  float* out = (float*)d_out;

  // workspace layout (bytes, 16B aligned); total ~218 MB (252 MB proven safe)
  char* ws = (char*)d_ws;
  float*   C     = (float*)(ws);                     // 50048*256*4 = 51,249,152
  ushortT* x0b   = (ushortT*)(ws + 51249152);        // 19.2 MB (h2b overlays later)
  ushortT* h2b   = (ushortT*)(ws + 51249152);        // 25.6 MB (x0b dead by then)
  ushortT* h1b   = (ushortT*)(ws + 76849152);        // 25,600,000
  ushortT* aggB  = (ushortT*)(ws + 102449152);       // 50000*4*256*2 = 102,400,000
  ushortT* Wall1 = (ushortT*)(ws + 204849152);       // 13*256*192*2 = 1,277,952
  ushortT* Wall2 = (ushortT*)(ws + 206127104);       // 13*256*256*2 = 1,703,936
  int*     cnt   = (int*)(ws + 207831040);           // 2,400,000
  int*     off   = (int*)(ws + 210231040);           // 2,400,000
  int*     srcs  = (int*)(ws + 212631040);           // 3,200,000
  int*     fill  = (int*)(ws + 215831040);           // 2,400,000
  int*     bsum  = (int*)(ws + 218231040);           // 4 KB
  int*     bscan = (int*)(ws + 218235136);           // 4 KB

  dim3 blk(256);

  // ---- stage 0: features + CSR build + weight prep ----
  k_build_x0<<<dim3((NN * IN1) / 256), blk, 0, stream>>>(x, x0b);
  k_add_emb<<<dim3((NGENE * EMBD) / 256), blk, 0, stream>>>(gene_idx, gene_emb, x0b, NGENE);
  k_add_emb<<<dim3((NPATH * EMBD) / 256), blk, 0, stream>>>(path_idx, path_emb, x0b, NPATH);
  hipMemsetAsync(cnt, 0, NRK * 4, stream);
  hipMemsetAsync(fill, 0, NRK * 4, stream);
  k_count<<<dim3(NE / 256), blk, 0, stream>>>(edge_idx, edge_type, cnt);
  k_scan1<<<dim3(NSB), blk, 0, stream>>>(cnt, bsum);
  k_scan2<<<dim3(1), dim3(1024), 0, stream>>>(bsum, bscan);
  k_scan3<<<dim3(NSB), blk, 0, stream>>>(cnt, bscan, off);
  k_fill<<<dim3(NE / 256), blk, 0, stream>>>(edge_idx, edge_type, off, fill, srcs);
  k_troot<<<dim3((IN1 * HDIM) / 256), blk, 0, stream>>>(root1, Wall1, IN1);
  k_troot<<<dim3((HDIM * HDIM) / 256), blk, 0, stream>>>(root2, Wall2, HDIM);
  k_wcat<<<dim3((RR * HDIM * IN1) / 256), blk, 0, stream>>>(comp1, basis1, Wall1 + 256 * IN1, IN1);
  k_wcat<<<dim3((RR * HDIM * HDIM) / 256), blk, 0, stream>>>(comp2, basis2, Wall2 + 256 * HDIM, HDIM);

  dim3 agrid(NN), gblk(512), ggrid(391);

  // ---- conv1: chunks {root+r0-3}, {r4-7}, {r8-11 + attention} ----
  k_agg<<<agrid, blk, 0, stream>>>(srcs, off, cnt, x0b, aggB, IN1, 0);
  k_gemm<<<ggrid, gblk, 0, stream>>>(x0b, aggB, Wall1, C, bias1, nullptr, nullptr, IN1, 5, 0);
  k_agg<<<agrid, blk, 0, stream>>>(srcs, off, cnt, x0b, aggB, IN1, 4);
  k_gemm<<<ggrid, gblk, 0, stream>>>(x0b, aggB, Wall1 + (size_t)5 * 256 * IN1, C, bias1,
                                     nullptr, nullptr, IN1, 4, 1);
  k_agg<<<agrid, blk, 0, stream>>>(srcs, off, cnt, x0b, aggB, IN1, 8);
  k_gemm<<<ggrid, gblk, 0, stream>>>(x0b, aggB, Wall1 + (size_t)9 * 256 * IN1, C, bias1,
                                     att1, h1b, IN1, 4, 2);

  // ---- conv2 ----
  k_agg<<<agrid, blk, 0, stream>>>(srcs, off, cnt, h1b, aggB, HDIM, 0);
  k_gemm<<<ggrid, gblk, 0, stream>>>(h1b, aggB, Wall2, C, bias2, nullptr, nullptr, HDIM, 5, 0);
  k_agg<<<agrid, blk, 0, stream>>>(srcs, off, cnt, h1b, aggB, HDIM, 4);
  k_gemm<<<ggrid, gblk, 0, stream>>>(h1b, aggB, Wall2 + (size_t)5 * 256 * HDIM, C, bias2,
                                     nullptr, nullptr, HDIM, 4, 1);
  k_agg<<<agrid, blk, 0, stream>>>(srcs, off, cnt, h1b, aggB, HDIM, 8);
  k_gemm<<<ggrid, gblk, 0, stream>>>(h1b, aggB, Wall2 + (size_t)9 * 256 * HDIM, C, bias2,
                                     att2, h2b, HDIM, 4, 2);

  // ---- prediction head ----
  k_pred<<<dim3((NN * 12 + 255) / 256), blk, 0, stream>>>(h2b, pred_w, pred_b, out);
}

// Round 7
// 1201.692 us; speedup vs baseline: 1.5242x; 1.0455x over previous
//
#include <hip/hip_runtime.h>
#include <cstddef>

// ---- problem constants ----
#define NN     50000
#define NE     800000
#define IND    128
#define EMBD   64
#define IN1    192     // IND + EMBD
#define HDIM   256
#define RR     12
#define BB     8
#define NGENE  20000
#define NPATH  2000
#define NRK    (RR * NN)               // 600000 segment keys
#define SCB    1024
#define NSB    ((NRK + SCB - 1) / SCB) // 586

typedef __attribute__((ext_vector_type(8))) short short8;
typedef __attribute__((ext_vector_type(4))) float f32x4;
typedef unsigned short ushortT;

__device__ __forceinline__ float bu2f(unsigned short u) {
  unsigned int x = ((unsigned int)u) << 16;
  return __builtin_bit_cast(float, x);
}
__device__ __forceinline__ unsigned short f2bu(float f) {
  unsigned int x = __builtin_bit_cast(unsigned int, f);
  unsigned int r = (x + 0x7fffu + ((x >> 16) & 1u)) >> 16;
  return (unsigned short)r;
}

// ---------- build x0 = [x | 0] bf16 ----------
__global__ void k_build_x0(const float* __restrict__ x, ushortT* __restrict__ x0) {
  int t = blockIdx.x * 256 + threadIdx.x;
  if (t >= NN * IN1) return;
  int n = t / IN1, i = t - n * IN1;
  x0[t] = (i < IND) ? f2bu(x[(size_t)n * IND + i]) : (ushortT)0;
}

__global__ void k_add_emb(const int* __restrict__ idx, const float* __restrict__ emb,
                          ushortT* __restrict__ x0, int count) {
  int t = blockIdx.x * 256 + threadIdx.x;
  if (t >= count * EMBD) return;
  int g = t / EMBD, j = t - g * EMBD;
  x0[(size_t)idx[g] * IN1 + IND + j] = f2bu(emb[t]);
}

// ---------- per-(rel,dst) edge counts ----------
__global__ void k_count(const int* __restrict__ ei, const int* __restrict__ et,
                        int* __restrict__ cnt) {
  int e = blockIdx.x * 256 + threadIdx.x;
  if (e >= NE) return;
  atomicAdd(&cnt[et[e] * NN + ei[NE + e]], 1);
}

// ---------- 3-kernel exclusive scan ----------
__global__ __launch_bounds__(256) void k_scan1(const int* __restrict__ cnt,
                                               int* __restrict__ bsum) {
  __shared__ int lds[256];
  int t = threadIdx.x;
  int base = blockIdx.x * SCB + t * 4;
  int s = 0;
#pragma unroll
  for (int j = 0; j < 4; j++) { int idx = base + j; if (idx < NRK) s += cnt[idx]; }
  lds[t] = s; __syncthreads();
  for (int d = 128; d > 0; d >>= 1) { if (t < d) lds[t] += lds[t + d]; __syncthreads(); }
  if (t == 0) bsum[blockIdx.x] = lds[0];
}

__global__ __launch_bounds__(1024) void k_scan2(const int* __restrict__ bsum,
                                                int* __restrict__ bscan) {
  __shared__ int lds[1024];
  int t = threadIdx.x;
  int v = (t < NSB) ? bsum[t] : 0;
  lds[t] = v; __syncthreads();
  for (int d = 1; d < 1024; d <<= 1) {
    int add = (t >= d) ? lds[t - d] : 0; __syncthreads();
    lds[t] += add; __syncthreads();
  }
  if (t < NSB) bscan[t] = lds[t] - v;
}

__global__ __launch_bounds__(256) void k_scan3(const int* __restrict__ cnt,
                                               const int* __restrict__ bscan,
                                               int* __restrict__ off) {
  __shared__ int lds[256];
  int t = threadIdx.x;
  int base = blockIdx.x * SCB + t * 4;
  int v[4]; int s = 0;
#pragma unroll
  for (int j = 0; j < 4; j++) { int idx = base + j; v[j] = (idx < NRK) ? cnt[idx] : 0; s += v[j]; }
  lds[t] = s; __syncthreads();
  for (int d = 1; d < 256; d <<= 1) {
    int add = (t >= d) ? lds[t - d] : 0; __syncthreads();
    lds[t] += add; __syncthreads();
  }
  int ex = lds[t] - s + bscan[blockIdx.x];
#pragma unroll
  for (int j = 0; j < 4; j++) {
    int idx = base + j;
    if (idx < NRK) { off[idx] = ex; ex += v[j]; }
  }
}

// stores SRC node id directly
__global__ void k_fill(const int* __restrict__ ei, const int* __restrict__ et,
                       const int* __restrict__ off, int* __restrict__ fill,
                       int* __restrict__ srcs) {
  int e = blockIdx.x * 256 + threadIdx.x;
  if (e >= NE) return;
  int key = et[e] * NN + ei[NE + e];
  int pos = off[key] + atomicAdd(&fill[key], 1);
  srcs[pos] = ei[e];
}

// ---------- W[r][o][i] = bf16( sum_b comp[r,b]*basis[b,i,o] ) ----------
__global__ void k_wcat(const float* __restrict__ comp, const float* __restrict__ basis,
                       ushortT* __restrict__ W, int in_dim) {
  int t = blockIdx.x * 256 + threadIdx.x;
  int total = RR * HDIM * in_dim;
  if (t >= total) return;
  int i = t % in_dim;
  int o = (t / in_dim) & 255;
  int r = t / (in_dim * 256);
  float acc = 0.f;
#pragma unroll
  for (int b = 0; b < BB; b++)
    acc += comp[r * BB + b] * basis[((size_t)b * in_dim + i) * HDIM + o];
  W[t] = f2bu(acc);
}

__global__ void k_troot(const float* __restrict__ root, ushortT* __restrict__ rt,
                        int in_dim) {
  int t = blockIdx.x * 256 + threadIdx.x;
  if (t >= in_dim * HDIM) return;
  int i = t % in_dim, o = t / in_dim;
  rt[t] = f2bu(root[(size_t)i * HDIM + o]);
}

// ---------- CSR gather aggregation: one wave per (dst, rl); 4 rels per pass ----------
__global__ __launch_bounds__(256) void k_agg(const int* __restrict__ srcs,
                                             const int* __restrict__ off,
                                             const int* __restrict__ cnt,
                                             const ushortT* __restrict__ xin,
                                             ushortT* __restrict__ aggB,
                                             int in_dim, int r0) {
  int wave = (blockIdx.x * 256 + threadIdx.x) >> 6;
  int lane = threadIdx.x & 63;
  int dst = wave >> 2;
  int rl  = wave & 3;
  if (dst >= NN) return;
  int key = (r0 + rl) * NN + dst;
  int beg = off[key];
  int n   = cnt[key];
  bool act = lane * 4 < in_dim;
  float a0 = 0.f, a1 = 0.f, a2 = 0.f, a3 = 0.f;
  for (int p = 0; p < n; p++) {
    int src = srcs[beg + p];
    if (act) {
      ushort4 v = *(const ushort4*)(xin + (size_t)src * in_dim + lane * 4);
      a0 += bu2f(v.x); a1 += bu2f(v.y); a2 += bu2f(v.z); a3 += bu2f(v.w);
    }
  }
  if (act) {
    float s = 1.0f / (float)max(n, 1);
    ushort4 o;
    o.x = f2bu(a0 * s); o.y = f2bu(a1 * s); o.z = f2bu(a2 * s); o.w = f2bu(a3 * s);
    *(ushort4*)(aggB + ((size_t)dst * 4 + rl) * in_dim + lane * 4) = o;
  }
}

// ---------- multi-segment MFMA GEMM, 128x128 tile, 4 waves, double-buffered LDS ----------
// grid (2, 391): bn = blockIdx.x*128, bm = blockIdx.y*128
// mode 0: C = acc + bias  (first=1: seg0 streams xin, segs 1.. from aggB)
// mode 1: C += acc        (all segs from aggB)
// One barrier per K-tile: prefetch(t+1)->regs, MFMA on buf[cur], regs->buf[cur^1], sync.
__global__ __launch_bounds__(256, 3) void k_gemm(const ushortT* __restrict__ xin,
                                                 const ushortT* __restrict__ aggB,
                                                 const ushortT* __restrict__ Wchunk,
                                                 float* __restrict__ C,
                                                 const float* __restrict__ bias,
                                                 int in_dim, int nseg, int mode) {
  __shared__ ushortT As[2][128 * 64];
  const int tid = threadIdx.x;
  const int bn = blockIdx.x * 128;
  const int bm = blockIdx.y * 128;
  const int wv = tid >> 6, l = tid & 63;
  const int wr = wv >> 1, wc = wv & 1;
  const int lm = l & 15, lq = l >> 4;
  const int c8 = tid & 7;       // 16B chunk within 64-elem row
  const int r0 = tid >> 3;      // 0..31
  const int nkt = in_dim >> 6;
  const int first = (mode == 0) ? 1 : 0;
  const int totKt = nseg * nkt;

  f32x4 acc[4][4];
#pragma unroll
  for (int mt = 0; mt < 4; mt++)
#pragma unroll
    for (int nt = 0; nt < 4; nt++) acc[mt][nt] = (f32x4){0.f, 0.f, 0.f, 0.f};

  uint4 pv[4];
  // prefetch tile 0 and store into buf 0
  {
    const ushortT* ab; size_t str;
    if (first) { ab = xin; str = (size_t)in_dim; }
    else       { ab = aggB; str = (size_t)4 * in_dim; }
#pragma unroll
    for (int p = 0; p < 4; p++) {
      int row = r0 + p * 32, dst = bm + row;
      pv[p] = (dst < NN) ? *(const uint4*)(ab + (size_t)dst * str + c8 * 8)
                         : make_uint4(0u, 0u, 0u, 0u);
    }
#pragma unroll
    for (int p = 0; p < 4; p++) {
      int row = r0 + p * 32;
      *(uint4*)(&As[0][row * 64 + (c8 ^ (row & 7)) * 8]) = pv[p];
    }
  }
  __syncthreads();

  int cur = 0, segC = 0, ktC = 0;
  for (int t = 0; t < totKt; t++) {
    // issue prefetch for tile t+1
    int segP = segC, ktP = ktC + 1;
    if (ktP == nkt) { ktP = 0; segP++; }
    if (t + 1 < totKt) {
      const ushortT* ab; size_t str;
      if (first && segP == 0) { ab = xin; str = (size_t)in_dim; }
      else { int rl = segP - first; ab = aggB + (size_t)rl * in_dim; str = (size_t)4 * in_dim; }
      int koff = ktP * 64 + c8 * 8;
#pragma unroll
      for (int p = 0; p < 4; p++) {
        int row = r0 + p * 32, dst = bm + row;
        pv[p] = (dst < NN) ? *(const uint4*)(ab + (size_t)dst * str + koff)
                           : make_uint4(0u, 0u, 0u, 0u);
      }
    }
    // MFMA on As[cur]
    const ushortT* Wseg = Wchunk + (size_t)segC * 256 * in_dim + ktC * 64;
#pragma unroll
    for (int ks = 0; ks < 2; ks++) {
      short8 af[4], bf[4];
#pragma unroll
      for (int mt = 0; mt < 4; mt++) {
        int ar = wr * 64 + mt * 16 + lm;
        af[mt] = *(const short8*)(&As[cur][ar * 64 + (((ks * 4) + lq) ^ (ar & 7)) * 8]);
      }
#pragma unroll
      for (int nt = 0; nt < 4; nt++) {
        int orow = bn + wc * 64 + nt * 16 + lm;
        bf[nt] = *(const short8*)(Wseg + (size_t)orow * in_dim + ks * 32 + lq * 8);
      }
#pragma unroll
      for (int mt = 0; mt < 4; mt++)
#pragma unroll
        for (int nt = 0; nt < 4; nt++)
          acc[mt][nt] = __builtin_amdgcn_mfma_f32_16x16x32_bf16(af[mt], bf[nt],
                                                                acc[mt][nt], 0, 0, 0);
    }
    // store prefetched tile into the other buffer
    if (t + 1 < totKt) {
#pragma unroll
      for (int p = 0; p < 4; p++) {
        int row = r0 + p * 32;
        *(uint4*)(&As[cur ^ 1][row * 64 + (c8 ^ (row & 7)) * 8]) = pv[p];
      }
    }
    __syncthreads();
    cur ^= 1; segC = segP; ktC = ktP;
  }

  // ---- epilogue: through-LDS coalesced fp32 C write, 2 slices of 64 rows ----
  float* Asf = (float*)As;
  for (int s = 0; s < 2; s++) {
    __syncthreads();
    if (wr == s) {
#pragma unroll
      for (int mt = 0; mt < 4; mt++)
#pragma unroll
        for (int r = 0; r < 4; r++)
#pragma unroll
          for (int nt = 0; nt < 4; nt++)
            Asf[(mt * 16 + lq * 4 + r) * 128 + wc * 64 + nt * 16 + lm] = acc[mt][nt][r];
    }
    __syncthreads();
#pragma unroll
    for (int j = 0; j < 8; j++) {
      int f = j * 256 + tid;          // float4 index 0..2047
      int row = f >> 5, c4 = (f & 31) * 4;
      int grow = bm + s * 64 + row;
      if (grow < NN) {
        float4 v = *(float4*)(&Asf[row * 128 + c4]);
        float* cp = C + (size_t)grow * HDIM + bn + c4;
        if (mode == 1) {
          float4 o = *(float4*)cp;
          v.x += o.x; v.y += o.y; v.z += o.z; v.w += o.w;
        } else {
          v.x += bias[bn + c4]; v.y += bias[bn + c4 + 1];
          v.z += bias[bn + c4 + 2]; v.w += bias[bn + c4 + 3];
        }
        *(float4*)cp = v;
      }
    }
  }
}

// ---------- head-softmax attention: fp32 in, bf16 out; one wave per node ----------
__global__ void k_attn(const float* __restrict__ h, const float* __restrict__ att,
                       ushortT* __restrict__ hb) {
  int gtid = blockIdx.x * 256 + threadIdx.x;
  int node = gtid >> 6;
  int lane = gtid & 63;
  if (node >= NN) return;
  const float* hp = h + (size_t)node * HDIM;
  float v[4], s[4];
#pragma unroll
  for (int hd = 0; hd < 4; hd++) {
    v[hd] = hp[hd * 64 + lane];
    s[hd] = v[hd] * att[hd * 64 + lane];
  }
#pragma unroll
  for (int off = 32; off > 0; off >>= 1) {
#pragma unroll
    for (int hd = 0; hd < 4; hd++) s[hd] += __shfl_xor(s[hd], off, 64);
  }
  float mx = fmaxf(fmaxf(s[0], s[1]), fmaxf(s[2], s[3]));
  float ex[4], sum = 0.f;
#pragma unroll
  for (int hd = 0; hd < 4; hd++) { ex[hd] = __expf(s[hd] - mx); sum += ex[hd]; }
  float inv = 1.0f / sum;
  ushortT* ob = hb + (size_t)node * HDIM;
#pragma unroll
  for (int hd = 0; hd < 4; hd++) ob[hd * 64 + lane] = f2bu(v[hd] * (ex[hd] * inv));
}

// ---------- prediction head ----------
__global__ void k_pred(const ushortT* __restrict__ h, const float* __restrict__ w,
                       const float* __restrict__ b, float* __restrict__ out) {
  int t = blockIdx.x * 256 + threadIdx.x;
  if (t >= NN * 12) return;
  int n = t / 12, j = t - n * 12;
  float acc = b[j];
  const ushortT* hp = h + (size_t)n * HDIM;
#pragma unroll 4
  for (int k = 0; k < HDIM; k++) acc += bu2f(hp[k]) * w[k * 12 + j];
  out[t] = acc;
}

extern "C" void kernel_launch(void* const* d_in, const int* in_sizes, int n_in,
                              void* d_out, int out_size, void* d_ws, size_t ws_size,
                              hipStream_t stream) {
  const float* x         = (const float*)d_in[0];
  const int*   edge_idx  = (const int*)d_in[1];
  const int*   edge_type = (const int*)d_in[2];
  const int*   gene_idx  = (const int*)d_in[3];
  const int*   path_idx  = (const int*)d_in[4];
  const float* gene_emb  = (const float*)d_in[5];
  const float* path_emb  = (const float*)d_in[6];
  const float* comp1     = (const float*)d_in[7];
  const float* basis1    = (const float*)d_in[8];
  const float* root1     = (const float*)d_in[9];
  const float* bias1     = (const float*)d_in[10];
  const float* att1      = (const float*)d_in[11];
  const float* comp2     = (const float*)d_in[12];
  const float* basis2    = (const float*)d_in[13];
  const float* root2     = (const float*)d_in[14];
  const float* bias2     = (const float*)d_in[15];
  const float* att2      = (const float*)d_in[16];
  const float* pred_w    = (const float*)d_in[17];
  const float* pred_b    = (const float*)d_in[18];
  float* out = (float*)d_out;

  // workspace layout (bytes, 16B aligned); total ~218 MB (252 MB proven safe)
  char* ws = (char*)d_ws;
  float*   C     = (float*)(ws);                     // 50048*256*4 = 51,249,152
  ushortT* x0b   = (ushortT*)(ws + 51249152);        // 19.2 MB (h2b overlays later)
  ushortT* h2b   = (ushortT*)(ws + 51249152);        // 25.6 MB (x0b dead by then)
  ushortT* h1b   = (ushortT*)(ws + 76849152);        // 25,600,000
  ushortT* aggB  = (ushortT*)(ws + 102449152);       // 50000*4*256*2 = 102,400,000
  ushortT* Wall1 = (ushortT*)(ws + 204849152);       // 13*256*192*2 = 1,277,952
  ushortT* Wall2 = (ushortT*)(ws + 206127104);       // 13*256*256*2 = 1,703,936
  int*     cnt   = (int*)(ws + 207831040);           // 2,400,000
  int*     off   = (int*)(ws + 210231040);           // 2,400,000
  int*     srcs  = (int*)(ws + 212631040);           // 3,200,000
  int*     fill  = (int*)(ws + 215831040);           // 2,400,000
  int*     bsum  = (int*)(ws + 218231040);           // 4 KB
  int*     bscan = (int*)(ws + 218235136);           // 4 KB

  dim3 blk(256);

  // ---- stage 0: features + CSR build + weight prep ----
  k_build_x0<<<dim3((NN * IN1) / 256), blk, 0, stream>>>(x, x0b);
  k_add_emb<<<dim3((NGENE * EMBD) / 256), blk, 0, stream>>>(gene_idx, gene_emb, x0b, NGENE);
  k_add_emb<<<dim3((NPATH * EMBD) / 256), blk, 0, stream>>>(path_idx, path_emb, x0b, NPATH);
  hipMemsetAsync(cnt, 0, NRK * 4, stream);
  hipMemsetAsync(fill, 0, NRK * 4, stream);
  k_count<<<dim3(NE / 256), blk, 0, stream>>>(edge_idx, edge_type, cnt);
  k_scan1<<<dim3(NSB), blk, 0, stream>>>(cnt, bsum);
  k_scan2<<<dim3(1), dim3(1024), 0, stream>>>(bsum, bscan);
  k_scan3<<<dim3(NSB), blk, 0, stream>>>(cnt, bscan, off);
  k_fill<<<dim3(NE / 256), blk, 0, stream>>>(edge_idx, edge_type, off, fill, srcs);
  k_troot<<<dim3((IN1 * HDIM) / 256), blk, 0, stream>>>(root1, Wall1, IN1);
  k_troot<<<dim3((HDIM * HDIM) / 256), blk, 0, stream>>>(root2, Wall2, HDIM);
  k_wcat<<<dim3((RR * HDIM * IN1) / 256), blk, 0, stream>>>(comp1, basis1, Wall1 + 256 * IN1, IN1);
  k_wcat<<<dim3((RR * HDIM * HDIM) / 256), blk, 0, stream>>>(comp2, basis2, Wall2 + 256 * HDIM, HDIM);

  dim3 agrid(NN), gblk(256), ggrid(2, 391);
  dim3 ngrid((NN * 64 + 255) / 256);

  // ---- conv1: chunks {root+r0-3}, {r4-7}, {r8-11}, then attention ----
  k_agg<<<agrid, blk, 0, stream>>>(srcs, off, cnt, x0b, aggB, IN1, 0);
  k_gemm<<<ggrid, gblk, 0, stream>>>(x0b, aggB, Wall1, C, bias1, IN1, 5, 0);
  k_agg<<<agrid, blk, 0, stream>>>(srcs, off, cnt, x0b, aggB, IN1, 4);
  k_gemm<<<ggrid, gblk, 0, stream>>>(x0b, aggB, Wall1 + (size_t)5 * 256 * IN1, C, bias1, IN1, 4, 1);
  k_agg<<<agrid, blk, 0, stream>>>(srcs, off, cnt, x0b, aggB, IN1, 8);
  k_gemm<<<ggrid, gblk, 0, stream>>>(x0b, aggB, Wall1 + (size_t)9 * 256 * IN1, C, bias1, IN1, 4, 1);
  k_attn<<<ngrid, blk, 0, stream>>>(C, att1, h1b);

  // ---- conv2 ----
  k_agg<<<agrid, blk, 0, stream>>>(srcs, off, cnt, h1b, aggB, HDIM, 0);
  k_gemm<<<ggrid, gblk, 0, stream>>>(h1b, aggB, Wall2, C, bias2, HDIM, 5, 0);
  k_agg<<<agrid, blk, 0, stream>>>(srcs, off, cnt, h1b, aggB, HDIM, 4);
  k_gemm<<<ggrid, gblk, 0, stream>>>(h1b, aggB, Wall2 + (size_t)5 * 256 * HDIM, C, bias2, HDIM, 4, 1);
  k_agg<<<agrid, blk, 0, stream>>>(srcs, off, cnt, h1b, aggB, HDIM, 8);
  k_gemm<<<ggrid, gblk, 0, stream>>>(h1b, aggB, Wall2 + (size_t)9 * 256 * HDIM, C, bias2, HDIM, 4, 1);
  k_attn<<<ngrid, blk, 0, stream>>>(C, att2, h2b);

  // ---- prediction head ----
  k_pred<<<dim3((NN * 12 + 255) / 256), blk, 0, stream>>>(h2b, pred_w, pred_b, out);
}